// Round 7
// baseline (498.462 us; speedup 1.0000x reference)
//
#include <hip/hip_runtime.h>
#include <float.h>

// FeatPropagation k=3 NN interpolation, round 11: GRID PRUNING.
// R10 post-mortem: 4th pipeline structure (sched_barrier fence), 4th null --
// VGPR 60, dur 146.2. Cross-round invariant: busy rebalances (103-126us) but
// dur pinned at 146 => at the WORK floor (268M pair-evals), not a scheduling
// floor. Pivot (pre-committed in R10): reduce evals via exact spatial grid.
// 32^3 cells over [-4,4] (h=0.25); cell-sort points AND query ids (coherent
// waves); per-lane ring expansion with conservative bound
// ((r-1)h - e)^2 > d3 + 1e-3 (e = query cell-overhang from clamping; slack
// covers d2-formula-vs-geometry rounding). ~40x fewer evals. Selection = the
// SAME 5-op f64 packed-key net (R3/R9: cheapest exact), local point idx;
// scan-order independence of lex (d2,idx) min is HW-verified (R9b passed).
// Fallbacks: grid (ws>=4.6MB) -> R10 fused (146us) -> generic.
//
// PROTECTED (absmax 0.015625): d2 = (q2+s2) - 2*((qx*sx+qy*sy)+qz*sz), per-op
// f32 rounding (contract off, no fma, no reassociation), this exact order,
// everywhere d2/s2/q2 are computed; selection = lex min on (d2, local idx);
// weights w_i = (1/(sqrt(max(d2,1e-12))+1e-8))/sum, same op order. Do NOT
// switch to fma/dx^2 form.

#define QPL   2
#define QPB   128
#define SPLIT 8
#define KEY_INIT 0x7FEFFFFFFFFFFFFFULL

#define NCA   32                 // cells per axis
#define NC    (NCA * NCA * NCA)  // 32768 cells
#define GMIN  (-4.0f)
#define HCELL (0.25f)
#define INVH  (4.0f)
#define SLACK (1e-3f)

typedef float v2f __attribute__((ext_vector_type(2)));

__device__ __forceinline__ double mk_key(float d2, int j) {
    unsigned long long u =
        ((unsigned long long)(unsigned)__float_as_uint(d2) << 32) | (unsigned)j;
    return __longlong_as_double(u);
}

__device__ __forceinline__ v2f dist2_pair(const v2f qx2, const v2f qy2,
                                          const v2f qz2, const v2f q22,
                                          const float4 p) {
    #pragma clang fp contract(off)
    const v2f px = {p.x, p.x};
    const v2f py = {p.y, p.y};
    const v2f pz = {p.z, p.z};
    const v2f pw = {p.w, p.w};
    const v2f t0 = qx2 * px;
    const v2f t1 = qy2 * py;
    const v2f t2 = t0 + t1;
    const v2f t3 = qz2 * pz;
    const v2f cr = t2 + t3;
    const v2f qs = q22 + pw;
    const v2f cc = cr + cr;
    const v2f d2 = qs - cc;
    return d2;
}

__device__ __forceinline__ float dist2_scalar(float qx, float qy, float qz,
                                              float q2, const float4 p) {
    #pragma clang fp contract(off)
    const float t0 = qx * p.x;
    const float t1 = qy * p.y;
    const float t2 = t0 + t1;
    const float t3 = qz * p.z;
    const float cr = t2 + t3;
    const float qs = q2 + p.w;
    const float cc = cr + cr;
    const float d2 = qs - cc;
    return d2;
}

__device__ __forceinline__ float sum_sq3(float x, float y, float z) {
    return __fadd_rn(__fadd_rn(__fmul_rn(x, x), __fmul_rn(y, y)),
                     __fmul_rn(z, z));
}

__device__ __forceinline__ int clampi(int v, int lo, int hi) {
    return v < lo ? lo : (v > hi ? hi : v);
}

__device__ __forceinline__ void cell3(float x, float y, float z,
                                      int& cx, int& cy, int& cz) {
    cx = clampi((int)floorf((x - GMIN) * INVH), 0, NCA - 1);
    cy = clampi((int)floorf((y - GMIN) * INVH), 0, NCA - 1);
    cz = clampi((int)floorf((z - GMIN) * INVH), 0, NCA - 1);
}

// ---------------- grid build: histogram ----------------
__global__ void grid_histo(const float* __restrict__ xyz,
                           const float* __restrict__ new_xyz,
                           int* __restrict__ cnt, int* __restrict__ qcnt,
                           int N, int M, int B) {
    const int i = blockIdx.x * blockDim.x + threadIdx.x;
    const int totalP = B * N;
    if (i < totalP) {
        const int b = i / N;
        int cx, cy, cz;
        cell3(xyz[(size_t)i * 3 + 0], xyz[(size_t)i * 3 + 1],
              xyz[(size_t)i * 3 + 2], cx, cy, cz);
        atomicAdd(&cnt[b * NC + (cz * NCA + cy) * NCA + cx], 1);
    } else {
        const int qi = i - totalP;
        if (qi < B * M) {
            const int b = qi / M;
            int cx, cy, cz;
            cell3(new_xyz[(size_t)qi * 3 + 0], new_xyz[(size_t)qi * 3 + 1],
                  new_xyz[(size_t)qi * 3 + 2], cx, cy, cz);
            atomicAdd(&qcnt[b * NC + (cz * NCA + cy) * NCA + cx], 1);
        }
    }
}

// ---------------- grid build: per-(array,batch) exclusive scan ----------------
__global__ __launch_bounds__(256) void grid_scan(
    const int* __restrict__ cnt, int* __restrict__ start,
    const int* __restrict__ qcnt, int* __restrict__ qstart,
    int N, int M, int B) {
    const int blk = blockIdx.x;              // [0, 2B)
    const bool isQ = blk >= B;
    const int b = isQ ? blk - B : blk;
    const int* __restrict__ src = isQ ? qcnt : cnt;
    int* __restrict__ dst = isQ ? qstart : start;
    const int base = isQ ? b * M : b * N;
    const int t = threadIdx.x;
    const int CH = NC / 256;                 // 128 cells per thread

    int s = 0;
    for (int j = 0; j < CH; ++j) s += src[b * NC + t * CH + j];

    __shared__ int parts[256];
    parts[t] = s;
    __syncthreads();
    for (int off = 1; off < 256; off <<= 1) {
        int v = 0;
        if (t >= off) v = parts[t - off];
        __syncthreads();
        parts[t] += v;
        __syncthreads();
    }
    int run = base + (t == 0 ? 0 : parts[t - 1]);
    for (int j = 0; j < CH; ++j) {
        dst[b * NC + t * CH + j] = run;
        run += src[b * NC + t * CH + j];
    }
    if (!isQ && b == B - 1 && t == 255) dst[B * NC] = B * N;  // sentinel
}

// ---------------- grid build: scatter (cnt/qcnt reused as cursors) ----------------
__global__ void grid_scatter(const float* __restrict__ xyz,
                             const float* __restrict__ new_xyz,
                             int* __restrict__ cnt, int* __restrict__ qcnt,
                             const int* __restrict__ start,
                             const int* __restrict__ qstart,
                             float4* __restrict__ spts, int* __restrict__ sidx,
                             int* __restrict__ qsrt,
                             int N, int M, int B) {
    const int i = blockIdx.x * blockDim.x + threadIdx.x;
    const int totalP = B * N;
    if (i < totalP) {
        const int b = i / N;
        const float sx = xyz[(size_t)i * 3 + 0];
        const float sy = xyz[(size_t)i * 3 + 1];
        const float sz = xyz[(size_t)i * 3 + 2];
        int cx, cy, cz;
        cell3(sx, sy, sz, cx, cy, cz);
        const int g = b * NC + (cz * NCA + cy) * NCA + cx;
        const int slot = start[g] + (atomicSub(&cnt[g], 1) - 1);
        spts[slot] = make_float4(sx, sy, sz, sum_sq3(sx, sy, sz));
        sidx[slot] = i - b * N;              // local point index
    } else {
        const int qi = i - totalP;
        if (qi < B * M) {
            const int b = qi / M;
            int cx, cy, cz;
            cell3(new_xyz[(size_t)qi * 3 + 0], new_xyz[(size_t)qi * 3 + 1],
                  new_xyz[(size_t)qi * 3 + 2], cx, cy, cz);
            const int g = b * NC + (cz * NCA + cy) * NCA + cx;
            const int slot = qstart[g] + (atomicSub(&qcnt[g], 1) - 1);
            qsrt[slot] = qi;                 // global query id
        }
    }
}

// ---------------- grid KNN: one lane per (sorted) query ----------------
__global__ __launch_bounds__(256) void fp_knn_grid(
    const float* __restrict__ new_xyz,
    const float4* __restrict__ spts, const int* __restrict__ sidx,
    const int* __restrict__ start, const int* __restrict__ qsrt,
    int4* __restrict__ jb, float4* __restrict__ wb,
    int N, int M, int B) {
    const int p = blockIdx.x * blockDim.x + threadIdx.x;
    if (p >= B * M) return;
    const int qid = qsrt[p];
    const int b = qid / M;
    const int bNC = b * NC;

    const float qx = new_xyz[(size_t)qid * 3 + 0];
    const float qy = new_xyz[(size_t)qid * 3 + 1];
    const float qz = new_xyz[(size_t)qid * 3 + 2];
    const float q2 = sum_sq3(qx, qy, qz);

    int cx, cy, cz;
    cell3(qx, qy, qz, cx, cy, cz);

    // query overhang beyond its (clamped) cell box, Chebyshev
    const float bx0 = GMIN + (float)cx * HCELL;
    const float by0 = GMIN + (float)cy * HCELL;
    const float bz0 = GMIN + (float)cz * HCELL;
    const float ex = fmaxf(fmaxf(bx0 - qx, qx - (bx0 + HCELL)), 0.0f);
    const float ey = fmaxf(fmaxf(by0 - qy, qy - (by0 + HCELL)), 0.0f);
    const float ez = fmaxf(fmaxf(bz0 - qz, qz - (bz0 + HCELL)), 0.0f);
    const float e = fmaxf(ex, fmaxf(ey, ez));

    double k0 = __longlong_as_double(KEY_INIT), k1 = k0, k2 = k0;

    auto seg = [&](int x0, int x1, int cy2, int cz2) {
        const int rowbase = bNC + (cz2 * NCA + cy2) * NCA;
        const int j0 = start[rowbase + x0];
        const int j1 = start[rowbase + x1 + 1];
        for (int j = j0; j < j1; ++j) {
            const float4 pt = spts[j];
            const float d2 = dist2_scalar(qx, qy, qz, q2, pt);
            const double key = mk_key(d2, sidx[j]);
            const double n0 = fmin(key, k0);
            const double n1 = fmin(fmax(key, k0), k1);
            const double n2 = fmin(fmax(key, k1), k2);
            k0 = n0; k1 = n1; k2 = n2;
        }
    };

    seg(cx, cx, cy, cz);                     // ring 0
    for (int r = 1; r < NCA; ++r) {
        // stop if ring r cannot beat current 3rd-best (d3 NaN while <3 found)
        const float d3 = __uint_as_float(
            (unsigned)((unsigned long long)__double_as_longlong(k2) >> 32));
        const float lb = fmaxf(HCELL * (float)(r - 1) - e, 0.0f);
        if (lb * lb > d3 + SLACK) break;
        const int z0 = cz - r < 0 ? 0 : cz - r;
        const int z1 = cz + r > NCA - 1 ? NCA - 1 : cz + r;
        const int y0 = cy - r < 0 ? 0 : cy - r;
        const int y1 = cy + r > NCA - 1 ? NCA - 1 : cy + r;
        const int x0 = cx - r < 0 ? 0 : cx - r;
        const int x1 = cx + r > NCA - 1 ? NCA - 1 : cx + r;
        for (int cz2 = z0; cz2 <= z1; ++cz2) {
            const int adz = cz2 >= cz ? cz2 - cz : cz - cz2;
            for (int cy2 = y0; cy2 <= y1; ++cy2) {
                const int ady = cy2 >= cy ? cy2 - cy : cy - cy2;
                if (adz == r || ady == r) {
                    seg(x0, x1, cy2, cz2);   // full row is shell
                } else {
                    if (cx - r >= 0)      seg(cx - r, cx - r, cy2, cz2);
                    if (cx + r <= NCA - 1) seg(cx + r, cx + r, cy2, cz2);
                }
            }
        }
    }

    const unsigned long long u0 = __double_as_longlong(k0);
    const unsigned long long u1 = __double_as_longlong(k1);
    const unsigned long long u2 = __double_as_longlong(k2);
    const float d0 = __uint_as_float((unsigned)(u0 >> 32));
    const float d1 = __uint_as_float((unsigned)(u1 >> 32));
    const float d2f = __uint_as_float((unsigned)(u2 >> 32));
    const float e0 = sqrtf(fmaxf(d0, 1e-12f));
    const float e1 = sqrtf(fmaxf(d1, 1e-12f));
    const float e2 = sqrtf(fmaxf(d2f, 1e-12f));
    const float r0 = 1.0f / (e0 + 1e-8f);
    const float r1 = 1.0f / (e1 + 1e-8f);
    const float r2 = 1.0f / (e2 + 1e-8f);
    const float rs = r0 + r1 + r2;
    jb[qid] = make_int4((int)(u0 & 0xffffffffu), (int)(u1 & 0xffffffffu),
                        (int)(u2 & 0xffffffffu), 0);
    wb[qid] = make_float4(r0 / rs, r1 / rs, r2 / rs, 0.0f);
}

// ---------------- gather + blend (verified in R9) ----------------
__global__ __launch_bounds__(256, 8) void fp_gather(
    const float4* __restrict__ feat4, const int4* __restrict__ jb,
    const float4* __restrict__ wb, float4* __restrict__ out4,
    int N, int M) {
    const int tid  = threadIdx.x;
    const int lane = tid & 63;
    const int wv   = tid >> 6;
    const int qblk = blockIdx.x * 16;
    const int b    = qblk / M;
    const int src_base = b * N;
    #pragma unroll
    for (int t = 0; t < 4; ++t) {
        const int q = qblk + wv * 4 + t;
        const int4   J = jb[q];
        const float4 W = wb[q];
        const float4 f0 = feat4[(size_t)(src_base + J.x) * 64 + lane];
        const float4 f1 = feat4[(size_t)(src_base + J.y) * 64 + lane];
        const float4 f2 = feat4[(size_t)(src_base + J.z) * 64 + lane];
        const float u0 = W.x, u1 = W.y, u2 = W.z;
        float4 o;
        o.x = u0 * f0.x + u1 * f1.x + u2 * f2.x;
        o.y = u0 * f0.y + u1 * f1.y + u2 * f2.y;
        o.z = u0 * f0.z + u1 * f1.z + u2 * f2.z;
        o.w = u0 * f0.w + u1 * f1.w + u2 * f2.w;
        out4[(size_t)q * 64 + lane] = o;
    }
}

// ---------------- fused fallback (R10, 146us) ----------------
__global__ void pack_pts(const float* __restrict__ xyz,
                         float4* __restrict__ pts, int total) {
    int i = blockIdx.x * blockDim.x + threadIdx.x;
    if (i < total) {
        const float sx = xyz[(size_t)i * 3 + 0];
        const float sy = xyz[(size_t)i * 3 + 1];
        const float sz = xyz[(size_t)i * 3 + 2];
        pts[i] = make_float4(sx, sy, sz, sum_sq3(sx, sy, sz));
    }
}

template <int CHUNK>
__global__ __launch_bounds__(512, 4) void fp_knn_main(
    const float* __restrict__ new_xyz, const float4* __restrict__ pts,
    const float4* __restrict__ feat4, float4* __restrict__ out4,
    int N, int blocks_per_batch) {
    __shared__ double s_k[SPLIT][QPB][3];
    __shared__ float  s_w[QPB][3];
    __shared__ int    s_j[QPB][3];

    int g = blockIdx.x;
    if (gridDim.x == 512 && blocks_per_batch == 128) {
        const int xcd = g & 7, slot = g >> 3;
        g = (xcd >> 1) * 128 + (xcd & 1) * 64 + slot;
    }

    const int tid  = threadIdx.x;
    const int lane = tid & 63;
    const int b    = g / blocks_per_batch;
    const int src_base = b * N;
    const int m0 = g * QPB + lane;
    const int m1 = m0 + 64;

    const float q0x = new_xyz[(size_t)m0 * 3 + 0];
    const float q0y = new_xyz[(size_t)m0 * 3 + 1];
    const float q0z = new_xyz[(size_t)m0 * 3 + 2];
    const float q1x = new_xyz[(size_t)m1 * 3 + 0];
    const float q1y = new_xyz[(size_t)m1 * 3 + 1];
    const float q1z = new_xyz[(size_t)m1 * 3 + 2];
    const v2f qx2 = {q0x, q1x};
    const v2f qy2 = {q0y, q1y};
    const v2f qz2 = {q0z, q1z};
    const v2f q22 = {sum_sq3(q0x, q0y, q0z), sum_sq3(q1x, q1y, q1z)};

    const int cw    = tid >> 6;
    const int cbase = cw * CHUNK;
    const float4* __restrict__ cp = pts + src_base + cbase;

    double k00 = __longlong_as_double(KEY_INIT);
    double k01 = k00, k02 = k00;
    double k10 = k00, k11 = k00, k12 = k00;

    #pragma unroll 8
    for (int j = 0; j < CHUNK; ++j) {
        const float4 p = cp[j];
        const v2f d2 = dist2_pair(qx2, qy2, qz2, q22, p);
        const double ka = mk_key(d2.x, cbase + j);
        const double kb = mk_key(d2.y, cbase + j);
        const double a0 = fmin(ka, k00);
        const double a1 = fmin(fmax(ka, k00), k01);
        const double a2 = fmin(fmax(ka, k01), k02);
        k00 = a0; k01 = a1; k02 = a2;
        const double b0 = fmin(kb, k10);
        const double b1 = fmin(fmax(kb, k10), k11);
        const double b2 = fmin(fmax(kb, k11), k12);
        k10 = b0; k11 = b1; k12 = b2;
    }

    s_k[cw][lane][0]      = k00; s_k[cw][lane][1]      = k01; s_k[cw][lane][2]      = k02;
    s_k[cw][lane + 64][0] = k10; s_k[cw][lane + 64][1] = k11; s_k[cw][lane + 64][2] = k12;
    __syncthreads();

    if (tid < QPB) {
        double m0k = __longlong_as_double(KEY_INIT), m1k = m0k, m2k = m0k;
        #pragma unroll
        for (int ss = 0; ss < SPLIT; ++ss) {
            #pragma unroll
            for (int r = 0; r < 3; ++r) {
                const double d = s_k[ss][tid][r];
                const double n0 = fmin(d, m0k);
                const double n1 = fmin(fmax(d, m0k), m1k);
                const double n2 = fmin(fmax(d, m1k), m2k);
                m0k = n0; m1k = n1; m2k = n2;
            }
        }
        unsigned long long u0 = __double_as_longlong(m0k);
        unsigned long long u1 = __double_as_longlong(m1k);
        unsigned long long u2 = __double_as_longlong(m2k);
        const float d0 = __uint_as_float((unsigned)(u0 >> 32));
        const float d1 = __uint_as_float((unsigned)(u1 >> 32));
        const float d2 = __uint_as_float((unsigned)(u2 >> 32));
        const float e0 = sqrtf(fmaxf(d0, 1e-12f));
        const float e1 = sqrtf(fmaxf(d1, 1e-12f));
        const float e2 = sqrtf(fmaxf(d2, 1e-12f));
        const float r0 = 1.0f / (e0 + 1e-8f);
        const float r1 = 1.0f / (e1 + 1e-8f);
        const float r2 = 1.0f / (e2 + 1e-8f);
        const float rs = r0 + r1 + r2;
        s_w[tid][0] = r0 / rs; s_w[tid][1] = r1 / rs; s_w[tid][2] = r2 / rs;
        s_j[tid][0] = (int)(u0 & 0xffffffffu);
        s_j[tid][1] = (int)(u1 & 0xffffffffu);
        s_j[tid][2] = (int)(u2 & 0xffffffffu);
    }
    __syncthreads();

    const int wv    = tid >> 6;
    const int qbase = g * QPB;
    #pragma unroll 4
    for (int t = 0; t < QPB / SPLIT; ++t) {
        const int qq = wv * (QPB / SPLIT) + t;
        const int   a0 = s_j[qq][0], a1 = s_j[qq][1], a2 = s_j[qq][2];
        const float u0 = s_w[qq][0], u1 = s_w[qq][1], u2 = s_w[qq][2];
        const float4 f0 = feat4[(size_t)(src_base + a0) * 64 + lane];
        const float4 f1 = feat4[(size_t)(src_base + a1) * 64 + lane];
        const float4 f2 = feat4[(size_t)(src_base + a2) * 64 + lane];
        float4 o;
        o.x = u0 * f0.x + u1 * f1.x + u2 * f2.x;
        o.y = u0 * f0.y + u1 * f1.y + u2 * f2.y;
        o.z = u0 * f0.z + u1 * f1.z + u2 * f2.z;
        o.w = u0 * f0.w + u1 * f1.w + u2 * f2.w;
        out4[(size_t)(qbase + qq) * 64 + lane] = o;
    }
}

// Generic fallback (shape mismatch only).
__global__ void fp_knn_generic(
    const float* __restrict__ new_xyz, const float* __restrict__ xyz,
    const float* __restrict__ feat, float* __restrict__ out,
    int N, int M, int Btot) {
    const int m = blockIdx.x * blockDim.x + threadIdx.x;
    if (m >= Btot * M) return;
    const int b = m / M;
    const int src_base = b * N;
    const float qx = new_xyz[(size_t)m * 3 + 0];
    const float qy = new_xyz[(size_t)m * 3 + 1];
    const float qz = new_xyz[(size_t)m * 3 + 2];
    const float q2 = sum_sq3(qx, qy, qz);
    double k0 = __longlong_as_double(KEY_INIT), k1 = k0, k2 = k0;
    for (int j = 0; j < N; ++j) {
        const float sx = xyz[(size_t)(src_base + j) * 3 + 0];
        const float sy = xyz[(size_t)(src_base + j) * 3 + 1];
        const float sz = xyz[(size_t)(src_base + j) * 3 + 2];
        const float4 p = make_float4(sx, sy, sz, sum_sq3(sx, sy, sz));
        const float d2 = dist2_scalar(qx, qy, qz, q2, p);
        const double key = mk_key(d2, j);
        const double n0 = fmin(key, k0);
        const double n1 = fmin(fmax(key, k0), k1);
        const double n2 = fmin(fmax(key, k1), k2);
        k0 = n0; k1 = n1; k2 = n2;
    }
    unsigned long long u0 = __double_as_longlong(k0);
    unsigned long long u1 = __double_as_longlong(k1);
    unsigned long long u2 = __double_as_longlong(k2);
    const float e0 = sqrtf(fmaxf(__uint_as_float((unsigned)(u0 >> 32)), 1e-12f));
    const float e1 = sqrtf(fmaxf(__uint_as_float((unsigned)(u1 >> 32)), 1e-12f));
    const float e2 = sqrtf(fmaxf(__uint_as_float((unsigned)(u2 >> 32)), 1e-12f));
    const float r0 = 1.0f / (e0 + 1e-8f);
    const float r1 = 1.0f / (e1 + 1e-8f);
    const float r2 = 1.0f / (e2 + 1e-8f);
    const float rs = r0 + r1 + r2;
    const float w0 = r0 / rs, w1 = r1 / rs, w2 = r2 / rs;
    const int a0 = (int)(u0 & 0xffffffffu), a1 = (int)(u1 & 0xffffffffu),
              a2 = (int)(u2 & 0xffffffffu);
    const int C = 256;
    for (int c = 0; c < C; ++c) {
        out[(size_t)m * C + c] =
            w0 * feat[(size_t)(src_base + a0) * C + c] +
            w1 * feat[(size_t)(src_base + a1) * C + c] +
            w2 * feat[(size_t)(src_base + a2) * C + c];
    }
}

extern "C" void kernel_launch(void* const* d_in, const int* in_sizes, int n_in,
                              void* d_out, int out_size, void* d_ws, size_t ws_size,
                              hipStream_t stream) {
    const float* xyz     = (const float*)d_in[0];
    const float* new_xyz = (const float*)d_in[1];
    const float* feat    = (const float*)d_in[2];
    float* out = (float*)d_out;

    const int B = in_sizes[3];                 // 4
    const int N = in_sizes[0] / (3 * B);       // 4096
    const int M = in_sizes[1] / (3 * B);       // 16384
    const int Q = B * M;

    // ---- grid-path workspace layout (256-aligned) ----
    auto al = [](size_t x) { return (x + 255) & ~(size_t)255; };
    const size_t o_spts   = 0;
    const size_t o_sidx   = o_spts  + al((size_t)B * N * 16);
    const size_t o_cnt    = o_sidx  + al((size_t)B * N * 4);
    const size_t o_start  = o_cnt   + al((size_t)B * NC * 4);
    const size_t o_qcnt   = o_start + al(((size_t)B * NC + 1) * 4);
    const size_t o_qstart = o_qcnt  + al((size_t)B * NC * 4);
    const size_t o_qsort  = o_qstart+ al(((size_t)B * NC + 1) * 4);
    const size_t o_jb     = o_qsort + al((size_t)Q * 4);
    const size_t o_wb     = o_jb    + al((size_t)Q * 16);
    const size_t need_grid = o_wb   + al((size_t)Q * 16);

    if ((M % 16 == 0) && ws_size >= need_grid) {
        char* w = (char*)d_ws;
        float4* spts  = (float4*)(w + o_spts);
        int*   sidx   = (int*)  (w + o_sidx);
        int*   cnt    = (int*)  (w + o_cnt);
        int*   start  = (int*)  (w + o_start);
        int*   qcnt   = (int*)  (w + o_qcnt);
        int*   qstart = (int*)  (w + o_qstart);
        int*   qsrt   = (int*)  (w + o_qsort);
        int4*  jb     = (int4*) (w + o_jb);
        float4* wb    = (float4*)(w + o_wb);

        hipMemsetAsync(cnt,  0, (size_t)B * NC * 4, stream);
        hipMemsetAsync(qcnt, 0, (size_t)B * NC * 4, stream);
        const int items = B * N + B * M;
        grid_histo<<<(items + 255) / 256, 256, 0, stream>>>(
            xyz, new_xyz, cnt, qcnt, N, M, B);
        grid_scan<<<2 * B, 256, 0, stream>>>(cnt, start, qcnt, qstart, N, M, B);
        grid_scatter<<<(items + 255) / 256, 256, 0, stream>>>(
            xyz, new_xyz, cnt, qcnt, start, qstart, spts, sidx, qsrt, N, M, B);
        fp_knn_grid<<<(Q + 255) / 256, 256, 0, stream>>>(
            new_xyz, spts, sidx, start, qsrt, jb, wb, N, M, B);
        fp_gather<<<Q / 16, 256, 0, stream>>>(
            (const float4*)feat, jb, wb, (float4*)out, N, M);
        return;
    }

    const size_t pts_bytes = (size_t)(B * N) * sizeof(float4);
    const bool fused_ok = (N % SPLIT == 0) && (N / SPLIT == 512) &&
                          (M % QPB == 0) && (ws_size >= pts_bytes);
    if (fused_ok) {
        pack_pts<<<(B * N + 255) / 256, 256, 0, stream>>>(xyz, (float4*)d_ws, B * N);
        const int blocks = Q / QPB;
        fp_knn_main<512><<<blocks, 512, 0, stream>>>(
            new_xyz, (const float4*)d_ws, (const float4*)feat, (float4*)out,
            N, M / QPB);
    } else {
        fp_knn_generic<<<(Q + 255) / 256, 256, 0, stream>>>(
            new_xyz, xyz, feat, out, N, M, B);
    }
}

// Round 8
// 315.261 us; speedup vs baseline: 1.5811x; 1.5811x over previous
//
#include <hip/hip_runtime.h>
#include <float.h>

// FeatPropagation k=3 NN interpolation, round 12: grid select, LATENCY-SHAPED.
// R11 post-mortem: fp_knn_grid = 368us with VALUBusy 3.4%, Occ 2% -> pure
// exposed latency: (1) 1 lane/query = 1024 waves = 1 wave/SIMD, no TLP;
// (2) 32^3 grid = 0.125 pts/cell -> dozens of near-empty segments x 2
// dependent start[] loads each; (3) sparse-tail queries ring-expand far and
// hold their wave. Eval work itself ~4us. R12: SAME exact algorithm, but
// 16^3 grid (h=0.5, ~1pt/cell; rings 0-1 = 9 rows) and 4 lanes/query
// (262144 thr, 4096 waves, 16/CU): rows split ri%4==s (disjoint -> per-lane
// partials duplicate-free); stop-check/final via TEMPORARY butterfly merge
// (__shfl_xor 1,2 in aligned 4-group; partials never overwritten). Group-
// uniform stop decisions; cell-sorted queries keep groups convergent.
// Fallbacks: grid -> R10 fused (146us) -> generic.
//
// PROTECTED (absmax 0.015625): d2 = (q2+s2) - 2*((qx*sx+qy*sy)+qz*sz), per-op
// f32 rounding (contract off, no fma, no reassociation), this exact order,
// everywhere d2/s2/q2 are computed; selection = lex min on (d2, local idx);
// weights w_i = (1/(sqrt(max(d2,1e-12))+1e-8))/sum, same op order. Do NOT
// switch to fma/dx^2 form. Ring bound validated exact on this input (R11
// passed with identical absmax).

#define QPL   2
#define QPB   128
#define SPLIT 8
#define KEY_INIT 0x7FEFFFFFFFFFFFFFULL

#define NCA   16                 // cells per axis
#define NC    (NCA * NCA * NCA)  // 4096 cells
#define GMIN  (-4.0f)
#define HCELL (0.5f)
#define INVH  (2.0f)
#define SLACK (1e-3f)

typedef float v2f __attribute__((ext_vector_type(2)));

__device__ __forceinline__ double mk_key(float d2, int j) {
    unsigned long long u =
        ((unsigned long long)(unsigned)__float_as_uint(d2) << 32) | (unsigned)j;
    return __longlong_as_double(u);
}

__device__ __forceinline__ void ins3(double key, double& k0, double& k1,
                                     double& k2) {
    const double n0 = fmin(key, k0);
    const double n1 = fmin(fmax(key, k0), k1);
    const double n2 = fmin(fmax(key, k1), k2);
    k0 = n0; k1 = n1; k2 = n2;
}

__device__ __forceinline__ v2f dist2_pair(const v2f qx2, const v2f qy2,
                                          const v2f qz2, const v2f q22,
                                          const float4 p) {
    #pragma clang fp contract(off)
    const v2f px = {p.x, p.x};
    const v2f py = {p.y, p.y};
    const v2f pz = {p.z, p.z};
    const v2f pw = {p.w, p.w};
    const v2f t0 = qx2 * px;
    const v2f t1 = qy2 * py;
    const v2f t2 = t0 + t1;
    const v2f t3 = qz2 * pz;
    const v2f cr = t2 + t3;
    const v2f qs = q22 + pw;
    const v2f cc = cr + cr;
    const v2f d2 = qs - cc;
    return d2;
}

__device__ __forceinline__ float dist2_scalar(float qx, float qy, float qz,
                                              float q2, const float4 p) {
    #pragma clang fp contract(off)
    const float t0 = qx * p.x;
    const float t1 = qy * p.y;
    const float t2 = t0 + t1;
    const float t3 = qz * p.z;
    const float cr = t2 + t3;
    const float qs = q2 + p.w;
    const float cc = cr + cr;
    const float d2 = qs - cc;
    return d2;
}

__device__ __forceinline__ float sum_sq3(float x, float y, float z) {
    return __fadd_rn(__fadd_rn(__fmul_rn(x, x), __fmul_rn(y, y)),
                     __fmul_rn(z, z));
}

__device__ __forceinline__ int clampi(int v, int lo, int hi) {
    return v < lo ? lo : (v > hi ? hi : v);
}

__device__ __forceinline__ void cell3(float x, float y, float z,
                                      int& cx, int& cy, int& cz) {
    cx = clampi((int)floorf((x - GMIN) * INVH), 0, NCA - 1);
    cy = clampi((int)floorf((y - GMIN) * INVH), 0, NCA - 1);
    cz = clampi((int)floorf((z - GMIN) * INVH), 0, NCA - 1);
}

// ---------------- grid build: histogram ----------------
__global__ void grid_histo(const float* __restrict__ xyz,
                           const float* __restrict__ new_xyz,
                           int* __restrict__ cnt, int* __restrict__ qcnt,
                           int N, int M, int B) {
    const int i = blockIdx.x * blockDim.x + threadIdx.x;
    const int totalP = B * N;
    if (i < totalP) {
        const int b = i / N;
        int cx, cy, cz;
        cell3(xyz[(size_t)i * 3 + 0], xyz[(size_t)i * 3 + 1],
              xyz[(size_t)i * 3 + 2], cx, cy, cz);
        atomicAdd(&cnt[b * NC + (cz * NCA + cy) * NCA + cx], 1);
    } else {
        const int qi = i - totalP;
        if (qi < B * M) {
            const int b = qi / M;
            int cx, cy, cz;
            cell3(new_xyz[(size_t)qi * 3 + 0], new_xyz[(size_t)qi * 3 + 1],
                  new_xyz[(size_t)qi * 3 + 2], cx, cy, cz);
            atomicAdd(&qcnt[b * NC + (cz * NCA + cy) * NCA + cx], 1);
        }
    }
}

// ---------------- grid build: per-(array,batch) exclusive scan ----------------
__global__ __launch_bounds__(256) void grid_scan(
    const int* __restrict__ cnt, int* __restrict__ start,
    const int* __restrict__ qcnt, int* __restrict__ qstart,
    int N, int M, int B) {
    const int blk = blockIdx.x;              // [0, 2B)
    const bool isQ = blk >= B;
    const int b = isQ ? blk - B : blk;
    const int* __restrict__ src = isQ ? qcnt : cnt;
    int* __restrict__ dst = isQ ? qstart : start;
    const int base = isQ ? b * M : b * N;
    const int t = threadIdx.x;
    const int CH = NC / 256;                 // 16 cells per thread

    int s = 0;
    for (int j = 0; j < CH; ++j) s += src[b * NC + t * CH + j];

    __shared__ int parts[256];
    parts[t] = s;
    __syncthreads();
    for (int off = 1; off < 256; off <<= 1) {
        int v = 0;
        if (t >= off) v = parts[t - off];
        __syncthreads();
        parts[t] += v;
        __syncthreads();
    }
    int run = base + (t == 0 ? 0 : parts[t - 1]);
    for (int j = 0; j < CH; ++j) {
        dst[b * NC + t * CH + j] = run;
        run += src[b * NC + t * CH + j];
    }
    if (!isQ && b == B - 1 && t == 255) dst[B * NC] = B * N;  // sentinel
}

// ---------------- grid build: scatter (cnt/qcnt reused as cursors) ----------------
__global__ void grid_scatter(const float* __restrict__ xyz,
                             const float* __restrict__ new_xyz,
                             int* __restrict__ cnt, int* __restrict__ qcnt,
                             const int* __restrict__ start,
                             const int* __restrict__ qstart,
                             float4* __restrict__ spts, int* __restrict__ sidx,
                             int* __restrict__ qsrt,
                             int N, int M, int B) {
    const int i = blockIdx.x * blockDim.x + threadIdx.x;
    const int totalP = B * N;
    if (i < totalP) {
        const int b = i / N;
        const float sx = xyz[(size_t)i * 3 + 0];
        const float sy = xyz[(size_t)i * 3 + 1];
        const float sz = xyz[(size_t)i * 3 + 2];
        int cx, cy, cz;
        cell3(sx, sy, sz, cx, cy, cz);
        const int g = b * NC + (cz * NCA + cy) * NCA + cx;
        const int slot = start[g] + (atomicSub(&cnt[g], 1) - 1);
        spts[slot] = make_float4(sx, sy, sz, sum_sq3(sx, sy, sz));
        sidx[slot] = i - b * N;              // local point index
    } else {
        const int qi = i - totalP;
        if (qi < B * M) {
            const int b = qi / M;
            int cx, cy, cz;
            cell3(new_xyz[(size_t)qi * 3 + 0], new_xyz[(size_t)qi * 3 + 1],
                  new_xyz[(size_t)qi * 3 + 2], cx, cy, cz);
            const int g = b * NC + (cz * NCA + cy) * NCA + cx;
            const int slot = qstart[g] + (atomicSub(&qcnt[g], 1) - 1);
            qsrt[slot] = qi;                 // global query id
        }
    }
}

// ---------------- grid KNN: 4 lanes per (sorted) query ----------------
__global__ __launch_bounds__(256, 8) void fp_knn_grid(
    const float* __restrict__ new_xyz,
    const float4* __restrict__ spts, const int* __restrict__ sidx,
    const int* __restrict__ start, const int* __restrict__ qsrt,
    int4* __restrict__ jb, float4* __restrict__ wb,
    int N, int M, int B) {
    const int t = blockIdx.x * blockDim.x + threadIdx.x;
    const int p = t >> 2;                    // query slot
    const int s = t & 3;                     // sub-lane within 4-group
    if (p >= B * M) return;
    const int qid = qsrt[p];
    const int b = qid / M;
    const int bNC = b * NC;

    const float qx = new_xyz[(size_t)qid * 3 + 0];
    const float qy = new_xyz[(size_t)qid * 3 + 1];
    const float qz = new_xyz[(size_t)qid * 3 + 2];
    const float q2 = sum_sq3(qx, qy, qz);

    int cx, cy, cz;
    cell3(qx, qy, qz, cx, cy, cz);

    // query overhang beyond its (clamped) cell box, Chebyshev
    const float bx0 = GMIN + (float)cx * HCELL;
    const float by0 = GMIN + (float)cy * HCELL;
    const float bz0 = GMIN + (float)cz * HCELL;
    const float ex = fmaxf(fmaxf(bx0 - qx, qx - (bx0 + HCELL)), 0.0f);
    const float ey = fmaxf(fmaxf(by0 - qy, qy - (by0 + HCELL)), 0.0f);
    const float ez = fmaxf(fmaxf(bz0 - qz, qz - (bz0 + HCELL)), 0.0f);
    const float e = fmaxf(ex, fmaxf(ey, ez));

    // per-lane PARTIAL triple (disjoint rows -> no duplicates across lanes)
    double k0 = __longlong_as_double(KEY_INIT), k1 = k0, k2 = k0;

    auto seg = [&](int x0, int x1, int cy2, int cz2) {
        const int rowbase = bNC + (cz2 * NCA + cy2) * NCA;
        const int j0 = start[rowbase + x0];
        const int j1 = start[rowbase + x1 + 1];
        for (int j = j0; j < j1; ++j) {
            const float4 pt = spts[j];
            const float d2 = dist2_scalar(qx, qy, qz, q2, pt);
            ins3(mk_key(d2, sidx[j]), k0, k1, k2);
        }
    };

    // temporary-only butterfly merge of the 4 partial triples (group-local)
    auto merge4 = [&](double& o0, double& o1, double& o2) {
        double t0 = k0, t1 = k1, t2 = k2;
        #pragma unroll
        for (int mask = 1; mask <= 2; mask <<= 1) {
            const double r0 = __shfl_xor(t0, mask);
            const double r1 = __shfl_xor(t1, mask);
            const double r2 = __shfl_xor(t2, mask);
            ins3(r0, t0, t1, t2);
            ins3(r1, t0, t1, t2);
            ins3(r2, t0, t1, t2);
        }
        o0 = t0; o1 = t1; o2 = t2;
    };

    // rings 0..1: the 3x3 rows of the Chebyshev<=1 box, split ri%4==s
    {
        const int z0 = clampi(cz - 1, 0, NCA - 1), z1 = clampi(cz + 1, 0, NCA - 1);
        const int y0 = clampi(cy - 1, 0, NCA - 1), y1 = clampi(cy + 1, 0, NCA - 1);
        const int x0 = clampi(cx - 1, 0, NCA - 1), x1 = clampi(cx + 1, 0, NCA - 1);
        int ri = 0;
        for (int cz2 = z0; cz2 <= z1; ++cz2)
            for (int cy2 = y0; cy2 <= y1; ++cy2, ++ri)
                if ((ri & 3) == s) seg(x0, x1, cy2, cz2);
    }

    // extended rings with group-uniform stop check
    for (int r = 2; r < NCA; ++r) {
        double m0, m1, m2;
        merge4(m0, m1, m2);
        const float d3 = __uint_as_float(
            (unsigned)((unsigned long long)__double_as_longlong(m2) >> 32));
        const float lb = fmaxf(HCELL * (float)(r - 1) - e, 0.0f);
        if (lb * lb > d3 + SLACK) break;    // uniform within 4-group
        const int z0 = clampi(cz - r, 0, NCA - 1), z1 = clampi(cz + r, 0, NCA - 1);
        const int y0 = clampi(cy - r, 0, NCA - 1), y1 = clampi(cy + r, 0, NCA - 1);
        const int x0 = clampi(cx - r, 0, NCA - 1), x1 = clampi(cx + r, 0, NCA - 1);
        int ri = 0;
        for (int cz2 = z0; cz2 <= z1; ++cz2) {
            const int adz = cz2 >= cz ? cz2 - cz : cz - cz2;
            for (int cy2 = y0; cy2 <= y1; ++cy2) {
                const int ady = cy2 >= cy ? cy2 - cy : cy - cy2;
                if (adz == r || ady == r) {
                    if ((ri & 3) == s) seg(x0, x1, cy2, cz2);
                    ++ri;
                } else {
                    if (cx - r >= 0) {
                        if ((ri & 3) == s) seg(cx - r, cx - r, cy2, cz2);
                        ++ri;
                    }
                    if (cx + r <= NCA - 1) {
                        if ((ri & 3) == s) seg(cx + r, cx + r, cy2, cz2);
                        ++ri;
                    }
                }
            }
        }
    }

    double f0, f1, f2;
    merge4(f0, f1, f2);
    if (s == 0) {
        const unsigned long long u0 = __double_as_longlong(f0);
        const unsigned long long u1 = __double_as_longlong(f1);
        const unsigned long long u2 = __double_as_longlong(f2);
        const float d0 = __uint_as_float((unsigned)(u0 >> 32));
        const float d1 = __uint_as_float((unsigned)(u1 >> 32));
        const float d2f = __uint_as_float((unsigned)(u2 >> 32));
        const float e0 = sqrtf(fmaxf(d0, 1e-12f));
        const float e1 = sqrtf(fmaxf(d1, 1e-12f));
        const float e2 = sqrtf(fmaxf(d2f, 1e-12f));
        const float r0 = 1.0f / (e0 + 1e-8f);
        const float r1 = 1.0f / (e1 + 1e-8f);
        const float r2 = 1.0f / (e2 + 1e-8f);
        const float rs = r0 + r1 + r2;
        jb[qid] = make_int4((int)(u0 & 0xffffffffu), (int)(u1 & 0xffffffffu),
                            (int)(u2 & 0xffffffffu), 0);
        wb[qid] = make_float4(r0 / rs, r1 / rs, r2 / rs, 0.0f);
    }
}

// ---------------- gather + blend (verified in R9/R11) ----------------
__global__ __launch_bounds__(256, 8) void fp_gather(
    const float4* __restrict__ feat4, const int4* __restrict__ jb,
    const float4* __restrict__ wb, float4* __restrict__ out4,
    int N, int M) {
    const int tid  = threadIdx.x;
    const int lane = tid & 63;
    const int wv   = tid >> 6;
    const int qblk = blockIdx.x * 16;
    const int b    = qblk / M;
    const int src_base = b * N;
    #pragma unroll
    for (int t = 0; t < 4; ++t) {
        const int q = qblk + wv * 4 + t;
        const int4   J = jb[q];
        const float4 W = wb[q];
        const float4 f0 = feat4[(size_t)(src_base + J.x) * 64 + lane];
        const float4 f1 = feat4[(size_t)(src_base + J.y) * 64 + lane];
        const float4 f2 = feat4[(size_t)(src_base + J.z) * 64 + lane];
        const float u0 = W.x, u1 = W.y, u2 = W.z;
        float4 o;
        o.x = u0 * f0.x + u1 * f1.x + u2 * f2.x;
        o.y = u0 * f0.y + u1 * f1.y + u2 * f2.y;
        o.z = u0 * f0.z + u1 * f1.z + u2 * f2.z;
        o.w = u0 * f0.w + u1 * f1.w + u2 * f2.w;
        out4[(size_t)q * 64 + lane] = o;
    }
}

// ---------------- fused fallback (R10, 146us) ----------------
__global__ void pack_pts(const float* __restrict__ xyz,
                         float4* __restrict__ pts, int total) {
    int i = blockIdx.x * blockDim.x + threadIdx.x;
    if (i < total) {
        const float sx = xyz[(size_t)i * 3 + 0];
        const float sy = xyz[(size_t)i * 3 + 1];
        const float sz = xyz[(size_t)i * 3 + 2];
        pts[i] = make_float4(sx, sy, sz, sum_sq3(sx, sy, sz));
    }
}

template <int CHUNK>
__global__ __launch_bounds__(512, 4) void fp_knn_main(
    const float* __restrict__ new_xyz, const float4* __restrict__ pts,
    const float4* __restrict__ feat4, float4* __restrict__ out4,
    int N, int blocks_per_batch) {
    __shared__ double s_k[SPLIT][QPB][3];
    __shared__ float  s_w[QPB][3];
    __shared__ int    s_j[QPB][3];

    int g = blockIdx.x;
    if (gridDim.x == 512 && blocks_per_batch == 128) {
        const int xcd = g & 7, slot = g >> 3;
        g = (xcd >> 1) * 128 + (xcd & 1) * 64 + slot;
    }

    const int tid  = threadIdx.x;
    const int lane = tid & 63;
    const int b    = g / blocks_per_batch;
    const int src_base = b * N;
    const int m0 = g * QPB + lane;
    const int m1 = m0 + 64;

    const float q0x = new_xyz[(size_t)m0 * 3 + 0];
    const float q0y = new_xyz[(size_t)m0 * 3 + 1];
    const float q0z = new_xyz[(size_t)m0 * 3 + 2];
    const float q1x = new_xyz[(size_t)m1 * 3 + 0];
    const float q1y = new_xyz[(size_t)m1 * 3 + 1];
    const float q1z = new_xyz[(size_t)m1 * 3 + 2];
    const v2f qx2 = {q0x, q1x};
    const v2f qy2 = {q0y, q1y};
    const v2f qz2 = {q0z, q1z};
    const v2f q22 = {sum_sq3(q0x, q0y, q0z), sum_sq3(q1x, q1y, q1z)};

    const int cw    = tid >> 6;
    const int cbase = cw * CHUNK;
    const float4* __restrict__ cp = pts + src_base + cbase;

    double k00 = __longlong_as_double(KEY_INIT);
    double k01 = k00, k02 = k00;
    double k10 = k00, k11 = k00, k12 = k00;

    #pragma unroll 8
    for (int j = 0; j < CHUNK; ++j) {
        const float4 p = cp[j];
        const v2f d2 = dist2_pair(qx2, qy2, qz2, q22, p);
        ins3(mk_key(d2.x, cbase + j), k00, k01, k02);
        ins3(mk_key(d2.y, cbase + j), k10, k11, k12);
    }

    s_k[cw][lane][0]      = k00; s_k[cw][lane][1]      = k01; s_k[cw][lane][2]      = k02;
    s_k[cw][lane + 64][0] = k10; s_k[cw][lane + 64][1] = k11; s_k[cw][lane + 64][2] = k12;
    __syncthreads();

    if (tid < QPB) {
        double m0k = __longlong_as_double(KEY_INIT), m1k = m0k, m2k = m0k;
        #pragma unroll
        for (int ss = 0; ss < SPLIT; ++ss) {
            #pragma unroll
            for (int r = 0; r < 3; ++r) ins3(s_k[ss][tid][r], m0k, m1k, m2k);
        }
        unsigned long long u0 = __double_as_longlong(m0k);
        unsigned long long u1 = __double_as_longlong(m1k);
        unsigned long long u2 = __double_as_longlong(m2k);
        const float d0 = __uint_as_float((unsigned)(u0 >> 32));
        const float d1 = __uint_as_float((unsigned)(u1 >> 32));
        const float d2 = __uint_as_float((unsigned)(u2 >> 32));
        const float e0 = sqrtf(fmaxf(d0, 1e-12f));
        const float e1 = sqrtf(fmaxf(d1, 1e-12f));
        const float e2 = sqrtf(fmaxf(d2, 1e-12f));
        const float r0 = 1.0f / (e0 + 1e-8f);
        const float r1 = 1.0f / (e1 + 1e-8f);
        const float r2 = 1.0f / (e2 + 1e-8f);
        const float rs = r0 + r1 + r2;
        s_w[tid][0] = r0 / rs; s_w[tid][1] = r1 / rs; s_w[tid][2] = r2 / rs;
        s_j[tid][0] = (int)(u0 & 0xffffffffu);
        s_j[tid][1] = (int)(u1 & 0xffffffffu);
        s_j[tid][2] = (int)(u2 & 0xffffffffu);
    }
    __syncthreads();

    const int wv    = tid >> 6;
    const int qbase = g * QPB;
    #pragma unroll 4
    for (int t = 0; t < QPB / SPLIT; ++t) {
        const int qq = wv * (QPB / SPLIT) + t;
        const int   a0 = s_j[qq][0], a1 = s_j[qq][1], a2 = s_j[qq][2];
        const float u0 = s_w[qq][0], u1 = s_w[qq][1], u2 = s_w[qq][2];
        const float4 f0 = feat4[(size_t)(src_base + a0) * 64 + lane];
        const float4 f1 = feat4[(size_t)(src_base + a1) * 64 + lane];
        const float4 f2 = feat4[(size_t)(src_base + a2) * 64 + lane];
        float4 o;
        o.x = u0 * f0.x + u1 * f1.x + u2 * f2.x;
        o.y = u0 * f0.y + u1 * f1.y + u2 * f2.y;
        o.z = u0 * f0.z + u1 * f1.z + u2 * f2.z;
        o.w = u0 * f0.w + u1 * f1.w + u2 * f2.w;
        out4[(size_t)(qbase + qq) * 64 + lane] = o;
    }
}

// Generic fallback (shape mismatch only).
__global__ void fp_knn_generic(
    const float* __restrict__ new_xyz, const float* __restrict__ xyz,
    const float* __restrict__ feat, float* __restrict__ out,
    int N, int M, int Btot) {
    const int m = blockIdx.x * blockDim.x + threadIdx.x;
    if (m >= Btot * M) return;
    const int b = m / M;
    const int src_base = b * N;
    const float qx = new_xyz[(size_t)m * 3 + 0];
    const float qy = new_xyz[(size_t)m * 3 + 1];
    const float qz = new_xyz[(size_t)m * 3 + 2];
    const float q2 = sum_sq3(qx, qy, qz);
    double k0 = __longlong_as_double(KEY_INIT), k1 = k0, k2 = k0;
    for (int j = 0; j < N; ++j) {
        const float sx = xyz[(size_t)(src_base + j) * 3 + 0];
        const float sy = xyz[(size_t)(src_base + j) * 3 + 1];
        const float sz = xyz[(size_t)(src_base + j) * 3 + 2];
        const float4 p = make_float4(sx, sy, sz, sum_sq3(sx, sy, sz));
        const float d2 = dist2_scalar(qx, qy, qz, q2, p);
        ins3(mk_key(d2, j), k0, k1, k2);
    }
    unsigned long long u0 = __double_as_longlong(k0);
    unsigned long long u1 = __double_as_longlong(k1);
    unsigned long long u2 = __double_as_longlong(k2);
    const float e0 = sqrtf(fmaxf(__uint_as_float((unsigned)(u0 >> 32)), 1e-12f));
    const float e1 = sqrtf(fmaxf(__uint_as_float((unsigned)(u1 >> 32)), 1e-12f));
    const float e2 = sqrtf(fmaxf(__uint_as_float((unsigned)(u2 >> 32)), 1e-12f));
    const float r0 = 1.0f / (e0 + 1e-8f);
    const float r1 = 1.0f / (e1 + 1e-8f);
    const float r2 = 1.0f / (e2 + 1e-8f);
    const float rs = r0 + r1 + r2;
    const float w0 = r0 / rs, w1 = r1 / rs, w2 = r2 / rs;
    const int a0 = (int)(u0 & 0xffffffffu), a1 = (int)(u1 & 0xffffffffu),
              a2 = (int)(u2 & 0xffffffffu);
    const int C = 256;
    for (int c = 0; c < C; ++c) {
        out[(size_t)m * C + c] =
            w0 * feat[(size_t)(src_base + a0) * C + c] +
            w1 * feat[(size_t)(src_base + a1) * C + c] +
            w2 * feat[(size_t)(src_base + a2) * C + c];
    }
}

extern "C" void kernel_launch(void* const* d_in, const int* in_sizes, int n_in,
                              void* d_out, int out_size, void* d_ws, size_t ws_size,
                              hipStream_t stream) {
    const float* xyz     = (const float*)d_in[0];
    const float* new_xyz = (const float*)d_in[1];
    const float* feat    = (const float*)d_in[2];
    float* out = (float*)d_out;

    const int B = in_sizes[3];                 // 4
    const int N = in_sizes[0] / (3 * B);       // 4096
    const int M = in_sizes[1] / (3 * B);       // 16384
    const int Q = B * M;

    // ---- grid-path workspace layout (256-aligned) ----
    auto al = [](size_t x) { return (x + 255) & ~(size_t)255; };
    const size_t o_spts   = 0;
    const size_t o_sidx   = o_spts  + al((size_t)B * N * 16);
    const size_t o_cnt    = o_sidx  + al((size_t)B * N * 4);
    const size_t o_start  = o_cnt   + al((size_t)B * NC * 4);
    const size_t o_qcnt   = o_start + al(((size_t)B * NC + 1) * 4);
    const size_t o_qstart = o_qcnt  + al((size_t)B * NC * 4);
    const size_t o_qsort  = o_qstart+ al(((size_t)B * NC + 1) * 4);
    const size_t o_jb     = o_qsort + al((size_t)Q * 4);
    const size_t o_wb     = o_jb    + al((size_t)Q * 16);
    const size_t need_grid = o_wb   + al((size_t)Q * 16);

    if ((M % 16 == 0) && ws_size >= need_grid) {
        char* w = (char*)d_ws;
        float4* spts  = (float4*)(w + o_spts);
        int*   sidx   = (int*)  (w + o_sidx);
        int*   cnt    = (int*)  (w + o_cnt);
        int*   start  = (int*)  (w + o_start);
        int*   qcnt   = (int*)  (w + o_qcnt);
        int*   qstart = (int*)  (w + o_qstart);
        int*   qsrt   = (int*)  (w + o_qsort);
        int4*  jb     = (int4*) (w + o_jb);
        float4* wb    = (float4*)(w + o_wb);

        hipMemsetAsync(cnt,  0, (size_t)B * NC * 4, stream);
        hipMemsetAsync(qcnt, 0, (size_t)B * NC * 4, stream);
        const int items = B * N + B * M;
        grid_histo<<<(items + 255) / 256, 256, 0, stream>>>(
            xyz, new_xyz, cnt, qcnt, N, M, B);
        grid_scan<<<2 * B, 256, 0, stream>>>(cnt, start, qcnt, qstart, N, M, B);
        grid_scatter<<<(items + 255) / 256, 256, 0, stream>>>(
            xyz, new_xyz, cnt, qcnt, start, qstart, spts, sidx, qsrt, N, M, B);
        fp_knn_grid<<<(4 * Q + 255) / 256, 256, 0, stream>>>(
            new_xyz, spts, sidx, start, qsrt, jb, wb, N, M, B);
        fp_gather<<<Q / 16, 256, 0, stream>>>(
            (const float4*)feat, jb, wb, (float4*)out, N, M);
        return;
    }

    const size_t pts_bytes = (size_t)(B * N) * sizeof(float4);
    const bool fused_ok = (N % SPLIT == 0) && (N / SPLIT == 512) &&
                          (M % QPB == 0) && (ws_size >= pts_bytes);
    if (fused_ok) {
        pack_pts<<<(B * N + 255) / 256, 256, 0, stream>>>(xyz, (float4*)d_ws, B * N);
        const int blocks = Q / QPB;
        fp_knn_main<512><<<blocks, 512, 0, stream>>>(
            new_xyz, (const float4*)d_ws, (const float4*)feat, (float4*)out,
            N, M / QPB);
    } else {
        fp_knn_generic<<<(Q + 255) / 256, 256, 0, stream>>>(
            new_xyz, xyz, feat, out, N, M, B);
    }
}

// Round 9
// 199.487 us; speedup vs baseline: 2.4987x; 1.5804x over previous
//
#include <hip/hip_runtime.h>
#include <float.h>

// FeatPropagation k=3 NN interpolation, round 13: 16-lane groups + fused gather.
// R12 post-mortem: knn_grid 368->185us (busy 3.4->28%, occ 2->14%): direction
// right, shape still starved -- 4 lanes/query = only 4096 waves (4/SIMD), row-
// granular split idles lanes on the 9-row box, and ~75us of bench is dispatch
// envelope (7 dispatches x ~10-15us). R13: (1) 16 lanes/query, POINT-strided
// segments (coalesced spts reads, balanced, 16384 waves -> 8/SIMD); butterfly
// merge via __shfl_xor(..,16) on temporaries (disjoint strides = dup-free);
// (2) gather fused into the knn kernel (jb/wb in LDS; one less dispatch; knn
// overlaps gather HBM); (3) cnt/qcnt adjacent -> single memset. 5 dispatches.
// Grid/bound/PROTECTED math identical to R11/R12 (absmax-validated twice).
//
// PROTECTED (absmax 0.015625): d2 = (q2+s2) - 2*((qx*sx+qy*sy)+qz*sz), per-op
// f32 rounding (contract off, no fma, no reassociation), this exact order,
// everywhere d2/s2/q2 are computed; selection = lex min on (d2, local idx);
// weights w_i = (1/(sqrt(max(d2,1e-12))+1e-8))/sum, same op order. Do NOT
// switch to fma/dx^2 form.

#define QPL   2
#define QPB   128
#define SPLIT 8
#define KEY_INIT 0x7FEFFFFFFFFFFFFFULL

#define NCA   16                 // cells per axis
#define NC    (NCA * NCA * NCA)  // 4096 cells
#define GMIN  (-4.0f)
#define HCELL (0.5f)
#define INVH  (2.0f)
#define SLACK (1e-3f)

typedef float v2f __attribute__((ext_vector_type(2)));

__device__ __forceinline__ double mk_key(float d2, int j) {
    unsigned long long u =
        ((unsigned long long)(unsigned)__float_as_uint(d2) << 32) | (unsigned)j;
    return __longlong_as_double(u);
}

__device__ __forceinline__ void ins3(double key, double& k0, double& k1,
                                     double& k2) {
    const double n0 = fmin(key, k0);
    const double n1 = fmin(fmax(key, k0), k1);
    const double n2 = fmin(fmax(key, k1), k2);
    k0 = n0; k1 = n1; k2 = n2;
}

__device__ __forceinline__ v2f dist2_pair(const v2f qx2, const v2f qy2,
                                          const v2f qz2, const v2f q22,
                                          const float4 p) {
    #pragma clang fp contract(off)
    const v2f px = {p.x, p.x};
    const v2f py = {p.y, p.y};
    const v2f pz = {p.z, p.z};
    const v2f pw = {p.w, p.w};
    const v2f t0 = qx2 * px;
    const v2f t1 = qy2 * py;
    const v2f t2 = t0 + t1;
    const v2f t3 = qz2 * pz;
    const v2f cr = t2 + t3;
    const v2f qs = q22 + pw;
    const v2f cc = cr + cr;
    const v2f d2 = qs - cc;
    return d2;
}

__device__ __forceinline__ float dist2_scalar(float qx, float qy, float qz,
                                              float q2, const float4 p) {
    #pragma clang fp contract(off)
    const float t0 = qx * p.x;
    const float t1 = qy * p.y;
    const float t2 = t0 + t1;
    const float t3 = qz * p.z;
    const float cr = t2 + t3;
    const float qs = q2 + p.w;
    const float cc = cr + cr;
    const float d2 = qs - cc;
    return d2;
}

__device__ __forceinline__ float sum_sq3(float x, float y, float z) {
    return __fadd_rn(__fadd_rn(__fmul_rn(x, x), __fmul_rn(y, y)),
                     __fmul_rn(z, z));
}

__device__ __forceinline__ int clampi(int v, int lo, int hi) {
    return v < lo ? lo : (v > hi ? hi : v);
}

__device__ __forceinline__ void cell3(float x, float y, float z,
                                      int& cx, int& cy, int& cz) {
    cx = clampi((int)floorf((x - GMIN) * INVH), 0, NCA - 1);
    cy = clampi((int)floorf((y - GMIN) * INVH), 0, NCA - 1);
    cz = clampi((int)floorf((z - GMIN) * INVH), 0, NCA - 1);
}

// ---------------- grid build: histogram ----------------
__global__ void grid_histo(const float* __restrict__ xyz,
                           const float* __restrict__ new_xyz,
                           int* __restrict__ cnt, int* __restrict__ qcnt,
                           int N, int M, int B) {
    const int i = blockIdx.x * blockDim.x + threadIdx.x;
    const int totalP = B * N;
    if (i < totalP) {
        const int b = i / N;
        int cx, cy, cz;
        cell3(xyz[(size_t)i * 3 + 0], xyz[(size_t)i * 3 + 1],
              xyz[(size_t)i * 3 + 2], cx, cy, cz);
        atomicAdd(&cnt[b * NC + (cz * NCA + cy) * NCA + cx], 1);
    } else {
        const int qi = i - totalP;
        if (qi < B * M) {
            const int b = qi / M;
            int cx, cy, cz;
            cell3(new_xyz[(size_t)qi * 3 + 0], new_xyz[(size_t)qi * 3 + 1],
                  new_xyz[(size_t)qi * 3 + 2], cx, cy, cz);
            atomicAdd(&qcnt[b * NC + (cz * NCA + cy) * NCA + cx], 1);
        }
    }
}

// ---------------- grid build: per-(array,batch) exclusive scan ----------------
__global__ __launch_bounds__(256) void grid_scan(
    const int* __restrict__ cnt, int* __restrict__ start,
    const int* __restrict__ qcnt, int* __restrict__ qstart,
    int N, int M, int B) {
    const int blk = blockIdx.x;              // [0, 2B)
    const bool isQ = blk >= B;
    const int b = isQ ? blk - B : blk;
    const int* __restrict__ src = isQ ? qcnt : cnt;
    int* __restrict__ dst = isQ ? qstart : start;
    const int base = isQ ? b * M : b * N;
    const int t = threadIdx.x;
    const int CH = NC / 256;                 // 16 cells per thread

    int s = 0;
    for (int j = 0; j < CH; ++j) s += src[b * NC + t * CH + j];

    __shared__ int parts[256];
    parts[t] = s;
    __syncthreads();
    for (int off = 1; off < 256; off <<= 1) {
        int v = 0;
        if (t >= off) v = parts[t - off];
        __syncthreads();
        parts[t] += v;
        __syncthreads();
    }
    int run = base + (t == 0 ? 0 : parts[t - 1]);
    for (int j = 0; j < CH; ++j) {
        dst[b * NC + t * CH + j] = run;
        run += src[b * NC + t * CH + j];
    }
    if (!isQ && b == B - 1 && t == 255) dst[B * NC] = B * N;  // sentinel
}

// ---------------- grid build: scatter (cnt/qcnt reused as cursors) ----------------
__global__ void grid_scatter(const float* __restrict__ xyz,
                             const float* __restrict__ new_xyz,
                             int* __restrict__ cnt, int* __restrict__ qcnt,
                             const int* __restrict__ start,
                             const int* __restrict__ qstart,
                             float4* __restrict__ spts, int* __restrict__ sidx,
                             int* __restrict__ qsrt,
                             int N, int M, int B) {
    const int i = blockIdx.x * blockDim.x + threadIdx.x;
    const int totalP = B * N;
    if (i < totalP) {
        const int b = i / N;
        const float sx = xyz[(size_t)i * 3 + 0];
        const float sy = xyz[(size_t)i * 3 + 1];
        const float sz = xyz[(size_t)i * 3 + 2];
        int cx, cy, cz;
        cell3(sx, sy, sz, cx, cy, cz);
        const int g = b * NC + (cz * NCA + cy) * NCA + cx;
        const int slot = start[g] + (atomicSub(&cnt[g], 1) - 1);
        spts[slot] = make_float4(sx, sy, sz, sum_sq3(sx, sy, sz));
        sidx[slot] = i - b * N;              // local point index
    } else {
        const int qi = i - totalP;
        if (qi < B * M) {
            const int b = qi / M;
            int cx, cy, cz;
            cell3(new_xyz[(size_t)qi * 3 + 0], new_xyz[(size_t)qi * 3 + 1],
                  new_xyz[(size_t)qi * 3 + 2], cx, cy, cz);
            const int g = b * NC + (cz * NCA + cy) * NCA + cx;
            const int slot = qstart[g] + (atomicSub(&qcnt[g], 1) - 1);
            qsrt[slot] = qi;                 // global query id
        }
    }
}

// ---------------- fused: 16-lane-group grid KNN + feat gather ----------------
__global__ __launch_bounds__(256, 8) void fp_knn_gather(
    const float* __restrict__ new_xyz,
    const float4* __restrict__ spts, const int* __restrict__ sidx,
    const int* __restrict__ start, const int* __restrict__ qsrt,
    const float4* __restrict__ feat4, float4* __restrict__ out4,
    int N, int M, int B) {
    __shared__ int   s_jb[16][3];
    __shared__ float s_wb[16][3];
    __shared__ int   s_qid[16];

    const int tid = threadIdx.x;
    const int grp = tid >> 4;                // 16 groups per block
    const int s   = tid & 15;                // lane within group
    const int p   = blockIdx.x * 16 + grp;   // sorted query slot
    const int qid = qsrt[p];
    const int b   = qid / M;
    const int bNC = b * NC;

    const float qx = new_xyz[(size_t)qid * 3 + 0];
    const float qy = new_xyz[(size_t)qid * 3 + 1];
    const float qz = new_xyz[(size_t)qid * 3 + 2];
    const float q2 = sum_sq3(qx, qy, qz);

    int cx, cy, cz;
    cell3(qx, qy, qz, cx, cy, cz);

    // query overhang beyond its (clamped) cell box, Chebyshev
    const float bx0 = GMIN + (float)cx * HCELL;
    const float by0 = GMIN + (float)cy * HCELL;
    const float bz0 = GMIN + (float)cz * HCELL;
    const float ex = fmaxf(fmaxf(bx0 - qx, qx - (bx0 + HCELL)), 0.0f);
    const float ey = fmaxf(fmaxf(by0 - qy, qy - (by0 + HCELL)), 0.0f);
    const float ez = fmaxf(fmaxf(bz0 - qz, qz - (bz0 + HCELL)), 0.0f);
    const float e = fmaxf(ex, fmaxf(ey, ez));

    // per-lane PARTIAL triple; lanes take points j0+s, j0+s+16, ... (disjoint)
    double k0 = __longlong_as_double(KEY_INIT), k1 = k0, k2 = k0;

    auto seg = [&](int x0, int x1, int cy2, int cz2) {
        const int rowbase = bNC + (cz2 * NCA + cy2) * NCA;
        const int j0 = start[rowbase + x0];
        const int j1 = start[rowbase + x1 + 1];
        for (int j = j0 + s; j < j1; j += 16) {
            const float4 pt = spts[j];
            const float d2 = dist2_scalar(qx, qy, qz, q2, pt);
            ins3(mk_key(d2, sidx[j]), k0, k1, k2);
        }
    };

    // temporary-only butterfly merge of the 16 partial triples (group-local)
    auto merge16 = [&](double& o0, double& o1, double& o2) {
        double t0 = k0, t1 = k1, t2 = k2;
        #pragma unroll
        for (int mask = 1; mask <= 8; mask <<= 1) {
            const double r0 = __shfl_xor(t0, mask, 16);
            const double r1 = __shfl_xor(t1, mask, 16);
            const double r2 = __shfl_xor(t2, mask, 16);
            ins3(r0, t0, t1, t2);
            ins3(r1, t0, t1, t2);
            ins3(r2, t0, t1, t2);
        }
        o0 = t0; o1 = t1; o2 = t2;
    };

    // rings 0..1: full Chebyshev<=1 box (up to 9 rows), cooperative
    {
        const int z0 = clampi(cz - 1, 0, NCA - 1), z1 = clampi(cz + 1, 0, NCA - 1);
        const int y0 = clampi(cy - 1, 0, NCA - 1), y1 = clampi(cy + 1, 0, NCA - 1);
        const int x0 = clampi(cx - 1, 0, NCA - 1), x1 = clampi(cx + 1, 0, NCA - 1);
        for (int cz2 = z0; cz2 <= z1; ++cz2)
            for (int cy2 = y0; cy2 <= y1; ++cy2)
                seg(x0, x1, cy2, cz2);
    }

    // extended shells with group-uniform stop check
    for (int r = 2; r < NCA; ++r) {
        double m0, m1, m2;
        merge16(m0, m1, m2);
        const float d3 = __uint_as_float(
            (unsigned)((unsigned long long)__double_as_longlong(m2) >> 32));
        const float lb = fmaxf(HCELL * (float)(r - 1) - e, 0.0f);
        if (lb * lb > d3 + SLACK) break;    // uniform within 16-group
        const int z0 = clampi(cz - r, 0, NCA - 1), z1 = clampi(cz + r, 0, NCA - 1);
        const int y0 = clampi(cy - r, 0, NCA - 1), y1 = clampi(cy + r, 0, NCA - 1);
        const int x0 = clampi(cx - r, 0, NCA - 1), x1 = clampi(cx + r, 0, NCA - 1);
        for (int cz2 = z0; cz2 <= z1; ++cz2) {
            const int adz = cz2 >= cz ? cz2 - cz : cz - cz2;
            for (int cy2 = y0; cy2 <= y1; ++cy2) {
                const int ady = cy2 >= cy ? cy2 - cy : cy - cy2;
                if (adz == r || ady == r) {
                    seg(x0, x1, cy2, cz2);
                } else {
                    if (cx - r >= 0)       seg(cx - r, cx - r, cy2, cz2);
                    if (cx + r <= NCA - 1) seg(cx + r, cx + r, cy2, cz2);
                }
            }
        }
    }

    double f0, f1, f2;
    merge16(f0, f1, f2);
    if (s == 0) {
        const unsigned long long u0 = __double_as_longlong(f0);
        const unsigned long long u1 = __double_as_longlong(f1);
        const unsigned long long u2 = __double_as_longlong(f2);
        const float d0 = __uint_as_float((unsigned)(u0 >> 32));
        const float d1 = __uint_as_float((unsigned)(u1 >> 32));
        const float d2f = __uint_as_float((unsigned)(u2 >> 32));
        const float e0 = sqrtf(fmaxf(d0, 1e-12f));
        const float e1 = sqrtf(fmaxf(d1, 1e-12f));
        const float e2 = sqrtf(fmaxf(d2f, 1e-12f));
        const float r0 = 1.0f / (e0 + 1e-8f);
        const float r1 = 1.0f / (e1 + 1e-8f);
        const float r2 = 1.0f / (e2 + 1e-8f);
        const float rs = r0 + r1 + r2;
        s_jb[grp][0] = (int)(u0 & 0xffffffffu);
        s_jb[grp][1] = (int)(u1 & 0xffffffffu);
        s_jb[grp][2] = (int)(u2 & 0xffffffffu);
        s_wb[grp][0] = r0 / rs; s_wb[grp][1] = r1 / rs; s_wb[grp][2] = r2 / rs;
        s_qid[grp] = qid;
    }
    __syncthreads();

    // ---- phase B: gather + blend; 4 waves x 4 queries each ----
    const int lane = tid & 63;
    const int wv   = tid >> 6;
    #pragma unroll
    for (int t = 0; t < 4; ++t) {
        const int qq = wv * 4 + t;
        const int qid2 = s_qid[qq];
        const int b2 = qid2 / M;
        const int src_base = b2 * N;
        const int   a0 = s_jb[qq][0], a1 = s_jb[qq][1], a2 = s_jb[qq][2];
        const float u0 = s_wb[qq][0], u1 = s_wb[qq][1], u2 = s_wb[qq][2];
        const float4 f0v = feat4[(size_t)(src_base + a0) * 64 + lane];
        const float4 f1v = feat4[(size_t)(src_base + a1) * 64 + lane];
        const float4 f2v = feat4[(size_t)(src_base + a2) * 64 + lane];
        float4 o;
        o.x = u0 * f0v.x + u1 * f1v.x + u2 * f2v.x;
        o.y = u0 * f0v.y + u1 * f1v.y + u2 * f2v.y;
        o.z = u0 * f0v.z + u1 * f1v.z + u2 * f2v.z;
        o.w = u0 * f0v.w + u1 * f1v.w + u2 * f2v.w;
        out4[(size_t)qid2 * 64 + lane] = o;
    }
}

// ---------------- fused fallback (R10, 146us) ----------------
__global__ void pack_pts(const float* __restrict__ xyz,
                         float4* __restrict__ pts, int total) {
    int i = blockIdx.x * blockDim.x + threadIdx.x;
    if (i < total) {
        const float sx = xyz[(size_t)i * 3 + 0];
        const float sy = xyz[(size_t)i * 3 + 1];
        const float sz = xyz[(size_t)i * 3 + 2];
        pts[i] = make_float4(sx, sy, sz, sum_sq3(sx, sy, sz));
    }
}

template <int CHUNK>
__global__ __launch_bounds__(512, 4) void fp_knn_main(
    const float* __restrict__ new_xyz, const float4* __restrict__ pts,
    const float4* __restrict__ feat4, float4* __restrict__ out4,
    int N, int blocks_per_batch) {
    __shared__ double s_k[SPLIT][QPB][3];
    __shared__ float  s_w[QPB][3];
    __shared__ int    s_j[QPB][3];

    int g = blockIdx.x;
    if (gridDim.x == 512 && blocks_per_batch == 128) {
        const int xcd = g & 7, slot = g >> 3;
        g = (xcd >> 1) * 128 + (xcd & 1) * 64 + slot;
    }

    const int tid  = threadIdx.x;
    const int lane = tid & 63;
    const int b    = g / blocks_per_batch;
    const int src_base = b * N;
    const int m0 = g * QPB + lane;
    const int m1 = m0 + 64;

    const float q0x = new_xyz[(size_t)m0 * 3 + 0];
    const float q0y = new_xyz[(size_t)m0 * 3 + 1];
    const float q0z = new_xyz[(size_t)m0 * 3 + 2];
    const float q1x = new_xyz[(size_t)m1 * 3 + 0];
    const float q1y = new_xyz[(size_t)m1 * 3 + 1];
    const float q1z = new_xyz[(size_t)m1 * 3 + 2];
    const v2f qx2 = {q0x, q1x};
    const v2f qy2 = {q0y, q1y};
    const v2f qz2 = {q0z, q1z};
    const v2f q22 = {sum_sq3(q0x, q0y, q0z), sum_sq3(q1x, q1y, q1z)};

    const int cw    = tid >> 6;
    const int cbase = cw * CHUNK;
    const float4* __restrict__ cp = pts + src_base + cbase;

    double k00 = __longlong_as_double(KEY_INIT);
    double k01 = k00, k02 = k00;
    double k10 = k00, k11 = k00, k12 = k00;

    #pragma unroll 8
    for (int j = 0; j < CHUNK; ++j) {
        const float4 p = cp[j];
        const v2f d2 = dist2_pair(qx2, qy2, qz2, q22, p);
        ins3(mk_key(d2.x, cbase + j), k00, k01, k02);
        ins3(mk_key(d2.y, cbase + j), k10, k11, k12);
    }

    s_k[cw][lane][0]      = k00; s_k[cw][lane][1]      = k01; s_k[cw][lane][2]      = k02;
    s_k[cw][lane + 64][0] = k10; s_k[cw][lane + 64][1] = k11; s_k[cw][lane + 64][2] = k12;
    __syncthreads();

    if (tid < QPB) {
        double m0k = __longlong_as_double(KEY_INIT), m1k = m0k, m2k = m0k;
        #pragma unroll
        for (int ss = 0; ss < SPLIT; ++ss) {
            #pragma unroll
            for (int r = 0; r < 3; ++r) ins3(s_k[ss][tid][r], m0k, m1k, m2k);
        }
        unsigned long long u0 = __double_as_longlong(m0k);
        unsigned long long u1 = __double_as_longlong(m1k);
        unsigned long long u2 = __double_as_longlong(m2k);
        const float d0 = __uint_as_float((unsigned)(u0 >> 32));
        const float d1 = __uint_as_float((unsigned)(u1 >> 32));
        const float d2 = __uint_as_float((unsigned)(u2 >> 32));
        const float e0 = sqrtf(fmaxf(d0, 1e-12f));
        const float e1 = sqrtf(fmaxf(d1, 1e-12f));
        const float e2 = sqrtf(fmaxf(d2, 1e-12f));
        const float r0 = 1.0f / (e0 + 1e-8f);
        const float r1 = 1.0f / (e1 + 1e-8f);
        const float r2 = 1.0f / (e2 + 1e-8f);
        const float rs = r0 + r1 + r2;
        s_w[tid][0] = r0 / rs; s_w[tid][1] = r1 / rs; s_w[tid][2] = r2 / rs;
        s_j[tid][0] = (int)(u0 & 0xffffffffu);
        s_j[tid][1] = (int)(u1 & 0xffffffffu);
        s_j[tid][2] = (int)(u2 & 0xffffffffu);
    }
    __syncthreads();

    const int wv    = tid >> 6;
    const int qbase = g * QPB;
    #pragma unroll 4
    for (int t = 0; t < QPB / SPLIT; ++t) {
        const int qq = wv * (QPB / SPLIT) + t;
        const int   a0 = s_j[qq][0], a1 = s_j[qq][1], a2 = s_j[qq][2];
        const float u0 = s_w[qq][0], u1 = s_w[qq][1], u2 = s_w[qq][2];
        const float4 f0 = feat4[(size_t)(src_base + a0) * 64 + lane];
        const float4 f1 = feat4[(size_t)(src_base + a1) * 64 + lane];
        const float4 f2 = feat4[(size_t)(src_base + a2) * 64 + lane];
        float4 o;
        o.x = u0 * f0.x + u1 * f1.x + u2 * f2.x;
        o.y = u0 * f0.y + u1 * f1.y + u2 * f2.y;
        o.z = u0 * f0.z + u1 * f1.z + u2 * f2.z;
        o.w = u0 * f0.w + u1 * f1.w + u2 * f2.w;
        out4[(size_t)(qbase + qq) * 64 + lane] = o;
    }
}

// Generic fallback (shape mismatch only).
__global__ void fp_knn_generic(
    const float* __restrict__ new_xyz, const float* __restrict__ xyz,
    const float* __restrict__ feat, float* __restrict__ out,
    int N, int M, int Btot) {
    const int m = blockIdx.x * blockDim.x + threadIdx.x;
    if (m >= Btot * M) return;
    const int b = m / M;
    const int src_base = b * N;
    const float qx = new_xyz[(size_t)m * 3 + 0];
    const float qy = new_xyz[(size_t)m * 3 + 1];
    const float qz = new_xyz[(size_t)m * 3 + 2];
    const float q2 = sum_sq3(qx, qy, qz);
    double k0 = __longlong_as_double(KEY_INIT), k1 = k0, k2 = k0;
    for (int j = 0; j < N; ++j) {
        const float sx = xyz[(size_t)(src_base + j) * 3 + 0];
        const float sy = xyz[(size_t)(src_base + j) * 3 + 1];
        const float sz = xyz[(size_t)(src_base + j) * 3 + 2];
        const float4 p = make_float4(sx, sy, sz, sum_sq3(sx, sy, sz));
        const float d2 = dist2_scalar(qx, qy, qz, q2, p);
        ins3(mk_key(d2, j), k0, k1, k2);
    }
    unsigned long long u0 = __double_as_longlong(k0);
    unsigned long long u1 = __double_as_longlong(k1);
    unsigned long long u2 = __double_as_longlong(k2);
    const float e0 = sqrtf(fmaxf(__uint_as_float((unsigned)(u0 >> 32)), 1e-12f));
    const float e1 = sqrtf(fmaxf(__uint_as_float((unsigned)(u1 >> 32)), 1e-12f));
    const float e2 = sqrtf(fmaxf(__uint_as_float((unsigned)(u2 >> 32)), 1e-12f));
    const float r0 = 1.0f / (e0 + 1e-8f);
    const float r1 = 1.0f / (e1 + 1e-8f);
    const float r2 = 1.0f / (e2 + 1e-8f);
    const float rs = r0 + r1 + r2;
    const float w0 = r0 / rs, w1 = r1 / rs, w2 = r2 / rs;
    const int a0 = (int)(u0 & 0xffffffffu), a1 = (int)(u1 & 0xffffffffu),
              a2 = (int)(u2 & 0xffffffffu);
    const int C = 256;
    for (int c = 0; c < C; ++c) {
        out[(size_t)m * C + c] =
            w0 * feat[(size_t)(src_base + a0) * C + c] +
            w1 * feat[(size_t)(src_base + a1) * C + c] +
            w2 * feat[(size_t)(src_base + a2) * C + c];
    }
}

extern "C" void kernel_launch(void* const* d_in, const int* in_sizes, int n_in,
                              void* d_out, int out_size, void* d_ws, size_t ws_size,
                              hipStream_t stream) {
    const float* xyz     = (const float*)d_in[0];
    const float* new_xyz = (const float*)d_in[1];
    const float* feat    = (const float*)d_in[2];
    float* out = (float*)d_out;

    const int B = in_sizes[3];                 // 4
    const int N = in_sizes[0] / (3 * B);       // 4096
    const int M = in_sizes[1] / (3 * B);       // 16384
    const int Q = B * M;

    // ---- grid-path workspace layout (256-aligned; cnt/qcnt adjacent) ----
    auto al = [](size_t x) { return (x + 255) & ~(size_t)255; };
    const size_t o_spts   = 0;
    const size_t o_sidx   = o_spts  + al((size_t)B * N * 16);
    const size_t o_cnt    = o_sidx  + al((size_t)B * N * 4);
    const size_t o_qcnt   = o_cnt   + al((size_t)B * NC * 4);
    const size_t o_start  = o_qcnt  + al((size_t)B * NC * 4);
    const size_t o_qstart = o_start + al(((size_t)B * NC + 1) * 4);
    const size_t o_qsort  = o_qstart+ al(((size_t)B * NC + 1) * 4);
    const size_t need_grid = o_qsort + al((size_t)Q * 4);

    if ((Q % 16 == 0) && ws_size >= need_grid) {
        char* w = (char*)d_ws;
        float4* spts  = (float4*)(w + o_spts);
        int*   sidx   = (int*)  (w + o_sidx);
        int*   cnt    = (int*)  (w + o_cnt);
        int*   qcnt   = (int*)  (w + o_qcnt);
        int*   start  = (int*)  (w + o_start);
        int*   qstart = (int*)  (w + o_qstart);
        int*   qsrt   = (int*)  (w + o_qsort);

        // single memset over adjacent cnt+qcnt
        hipMemsetAsync(cnt, 0, o_start - o_cnt, stream);
        const int items = B * N + B * M;
        grid_histo<<<(items + 255) / 256, 256, 0, stream>>>(
            xyz, new_xyz, cnt, qcnt, N, M, B);
        grid_scan<<<2 * B, 256, 0, stream>>>(cnt, start, qcnt, qstart, N, M, B);
        grid_scatter<<<(items + 255) / 256, 256, 0, stream>>>(
            xyz, new_xyz, cnt, qcnt, start, qstart, spts, sidx, qsrt, N, M, B);
        fp_knn_gather<<<Q / 16, 256, 0, stream>>>(
            new_xyz, spts, sidx, start, qsrt, (const float4*)feat,
            (float4*)out, N, M, B);
        return;
    }

    const size_t pts_bytes = (size_t)(B * N) * sizeof(float4);
    const bool fused_ok = (N % SPLIT == 0) && (N / SPLIT == 512) &&
                          (M % QPB == 0) && (ws_size >= pts_bytes);
    if (fused_ok) {
        pack_pts<<<(B * N + 255) / 256, 256, 0, stream>>>(xyz, (float4*)d_ws, B * N);
        const int blocks = Q / QPB;
        fp_knn_main<512><<<blocks, 512, 0, stream>>>(
            new_xyz, (const float4*)d_ws, (const float4*)feat, (float4*)out,
            N, M / QPB);
    } else {
        fp_knn_generic<<<(Q + 255) / 256, 256, 0, stream>>>(
            new_xyz, xyz, feat, out, N, M, B);
    }
}